// Round 12
// baseline (798.414 us; speedup 1.0000x reference)
//
#include <hip/hip_runtime.h>

#define NPTS   262144
#define NBALLS 8192
#define MSZ    32

typedef unsigned short u16;
typedef __attribute__((ext_vector_type(8))) unsigned short u16x8;
typedef __attribute__((ext_vector_type(4))) unsigned short u16x4;
typedef __attribute__((ext_vector_type(8))) __bf16 bf16x8;
typedef __attribute__((ext_vector_type(4))) float f32x4;
typedef __attribute__((ext_vector_type(2))) unsigned u32x2;

__device__ inline u16 f2bf(float f) {
    unsigned u = __builtin_bit_cast(unsigned, f);
    u += 0x7fffu + ((u >> 16) & 1u);           // RNE
    return (u16)(u >> 16);
}

__device__ inline unsigned pk2(float lo, float hi) {   // lo -> bits 0-15
    return (unsigned)f2bf(lo) | ((unsigned)f2bf(hi) << 16);
}

__device__ inline f32x4 mfma16(u16x8 a, u16x8 b, f32x4 c) {
    return __builtin_amdgcn_mfma_f32_16x16x32_bf16(
        __builtin_bit_cast(bf16x8, a), __builtin_bit_cast(bf16x8, b), c, 0, 0, 0);
}

__device__ inline void gload_lds16(const u16* g, u16* l) {
    __builtin_amdgcn_global_load_lds(
        (const __attribute__((address_space(1))) void*)g,
        (__attribute__((address_space(3))) void*)l, 16, 0, 0);
}

// ---------------- K0: weight prep (round-9 verified, reverted) ---------------
__global__ __launch_bounds__(256) void k0_wprep(const float* __restrict__ w_qkv,
                                                const float* __restrict__ b_qkv,
                                                const float* __restrict__ w_proj,
                                                u16* __restrict__ wqkvT,
                                                u16* __restrict__ wpF,
                                                float* __restrict__ bq) {
    int idx = blockIdx.x * 256 + threadIdx.x;
    if (idx < 768 * 256) {
        int cp = idx >> 8, r = idx & 255;
        int k = cp >> 8, rem = cp & 255, h = rem >> 5, e = rem & 31;
        int orig = h * 96 + e * 3 + k;
        wqkvT[cp * 256 + r] = f2bf(w_qkv[r * 768 + orig]);
        if (r == 0) bq[cp] = b_qkv[orig];
    } else {
        int tid2 = idx - 768 * 256;             // < 8192 (grid = 800 blocks)
        int lane = tid2 & 63, ch = tid2 >> 6;
        int hk = ch & 7, gct = ch >> 3;
        int r15 = lane & 15, g4 = lane >> 4;
        u16x8 o;
#pragma unroll
        for (int j = 0; j < 8; ++j)
            o[j] = f2bf(w_proj[(size_t)(hk * 32 + g4 * 8 + j) * 256 + gct * 16 + r15]);
        *(u16x8*)&wpF[(size_t)tid2 * 8] = o;
    }
}

// ---------------- K1: fused pos-embed + QKV GEMM, 4 blocks/CU ---------------
// 256 thr (4 waves), 64-row panel (2 balls), 6 col-tiles. A-frags built
// directly in registers (embed once per panel); B LDS dbuf (R9-verified sync).
__global__ __launch_bounds__(256, 4) void k1_qkv(const float* __restrict__ x,
                                                 const float* __restrict__ pos,
                                                 const float* __restrict__ w_pe,
                                                 const float* __restrict__ b_pe,
                                                 const u16* __restrict__ wqkvT,
                                                 const float* __restrict__ bq,
                                                 u16* __restrict__ qkv2) {
    __shared__ __align__(16) u16 Bs[2][128 * 64];   // 32 KB dbuf
    __shared__ float ps_s[192];
    __shared__ float ctr_s[2][3];
    __shared__ float rel_s[64][3];
    __shared__ float wpe_s[3][256];
    __shared__ float bpe_s[256];

    int id = blockIdx.x;
    int rt = (id >> 3) + (id & 7) * 512;            // bijective XCD swizzle (4096%8==0)
    int t = threadIdx.x;
    int lane = t & 63, wv = t >> 6;
    int r15 = lane & 15, g4 = lane >> 4;
    int wr = wv >> 1, wc = wv & 1;
    int rowbase = rt * 64;

    // ---- tables + early B-stage (ct0,kt0) ----
    if (t < 192) ps_s[t] = pos[(size_t)rt * 192 + t];
    bpe_s[t] = b_pe[t];
    for (int i = t; i < 768; i += 256) ((float*)wpe_s)[i] = w_pe[i];
#pragma unroll
    for (int i = 0; i < 4; ++i) {
        int c = i * 256 + t;
        int row = c >> 3, sg = c & 7;
        gload_lds16(&wqkvT[(size_t)row * 256 + (sg ^ (row & 7)) * 8], &Bs[0][c * 8]);
    }
    __syncthreads();
    if (t < 6) {
        int b = t / 3, m = t % 3;
        float s = 0.f;
#pragma unroll
        for (int j = 0; j < MSZ; ++j) s += ps_s[(b * 32 + j) * 3 + m];
        ctr_s[b][m] = s * (1.0f / MSZ);
    }
    __syncthreads();
    if (t < 192) {
        int p = t / 3, m = t % 3;
        ((float*)rel_s)[t] = ps_s[t] - ctr_s[p >> 5][m];
    }
    __syncthreads();                                // rel_s ready

    // ---- embed directly into register A-frags (same layout as R9's af) ----
    u16x8 af[2][8];
#pragma unroll
    for (int i = 0; i < 2; ++i) {
        int lrow = wr * 32 + i * 16 + r15;
        size_t xbase = (size_t)(rowbase + lrow) * 256;
        float r0 = rel_s[lrow][0], r1 = rel_s[lrow][1], r2 = rel_s[lrow][2];
#pragma unroll
        for (int ks = 0; ks < 8; ++ks) {
            int k0 = ks * 32 + g4 * 8;
            float4 xa = *(const float4*)&x[xbase + k0];
            float4 xb = *(const float4*)&x[xbase + k0 + 4];
            u16x8 o;
#pragma unroll
            for (int m = 0; m < 8; ++m) {
                float xv = (m < 4) ? ((const float*)&xa)[m] : ((const float*)&xb)[m - 4];
                float v = fmaf(r0, wpe_s[0][k0 + m],
                          fmaf(r1, wpe_s[1][k0 + m],
                          fmaf(r2, wpe_s[2][k0 + m], xv))) + bpe_s[k0 + m];
                o[m] = f2bf(v);
            }
            af[i][ks] = o;
        }
    }

    // ---- main loop: 6 ct × 4 kt, B dbuf, R9-verified barrier scheme ----
    f32x4 acc[4][2];
#pragma unroll
    for (int j = 0; j < 4; ++j)
#pragma unroll
        for (int i = 0; i < 2; ++i) acc[j][i] = (f32x4){0.f, 0.f, 0.f, 0.f};

    const int ball = rt * 2 + wr;
#pragma unroll
    for (int ct = 0; ct < 6; ++ct) {
#pragma unroll
        for (int kt = 0; kt < 4; ++kt) {
            int cur = kt & 1;
            int it = ct * 4 + kt;
            if (it < 23) {
                int nit = it + 1, nct = nit >> 2, nkt = nit & 3;
#pragma unroll
                for (int i = 0; i < 4; ++i) {
                    int c = i * 256 + t;
                    int row = c >> 3, sg = c & 7;
                    gload_lds16(&wqkvT[(size_t)(nct * 128 + row) * 256 + nkt * 64 + (sg ^ (row & 7)) * 8],
                                &Bs[cur ^ 1][c * 8]);
                }
            }
#pragma unroll
            for (int ks = 0; ks < 2; ++ks) {
                u16x8 b[4];
#pragma unroll
                for (int j = 0; j < 4; ++j) {
                    int C = wc * 64 + j * 16 + r15;
                    b[j] = *(const u16x8*)&Bs[cur][C * 64 + (((ks * 4 + g4) ^ (C & 7)) * 8)];
                }
                // swapped operands: C rows = cp (in-thread), cols = point (lane)
#pragma unroll
                for (int j = 0; j < 4; ++j)
#pragma unroll
                    for (int i = 0; i < 2; ++i)
                        acc[j][i] = mfma16(b[j], af[i][2 * kt + ks], acc[j][i]);
            }
            if (kt == 3) {
                // epilogue for this ct: packed 8B stores (round-8 verified)
#pragma unroll
                for (int j = 0; j < 4; ++j) {
                    int cp0 = ct * 128 + wc * 64 + j * 16 + g4 * 4;
                    float4 bias = *(const float4*)&bq[cp0];
                    int mat = cp0 >> 8, rem = cp0 & 255, h = rem >> 5, e0 = rem & 31;
                    size_t base = (size_t)ball * 24576 + mat * 8192 + h * 1024 + e0;
#pragma unroll
                    for (int i = 0; i < 2; ++i) {
                        int point = i * 16 + r15;
                        unsigned lo = pk2(acc[j][i][0] + bias.x, acc[j][i][1] + bias.y);
                        unsigned hi = pk2(acc[j][i][2] + bias.z, acc[j][i][3] + bias.w);
                        *(u32x2*)&qkv2[base + point * 32] = (u32x2){lo, hi};
                        acc[j][i] = (f32x4){0.f, 0.f, 0.f, 0.f};
                    }
                }
            }
            __syncthreads();
        }
    }
}

// ---------------- K23: fused attention + projection (round-7 verified) ------
__global__ __launch_bounds__(256) void k23_attnproj(const float* __restrict__ pos,
                                                    const float* __restrict__ sigma,
                                                    const u16* __restrict__ qkv2,
                                                    const u16* __restrict__ wpF,
                                                    const float* __restrict__ bp,
                                                    float* __restrict__ out) {
    int ball = blockIdx.x, t = threadIdx.x;
    __shared__ float ps[MSZ][3];
    __shared__ float dist_s[MSZ][33];
    __shared__ __align__(16) u16 V_s[MSZ][256];
    __shared__ __align__(16) u16 P_s[4][MSZ][40];
    __shared__ __align__(16) u16 ao_s[MSZ][264];

    const size_t ballbase = (size_t)ball * 24576;

    if (t < MSZ * 3) ((float*)ps)[t] = pos[(size_t)ball * (MSZ * 3) + t];
    __syncthreads();
    for (int p = t; p < 1024; p += 256) {
        int m = p >> 5, k = p & 31;
        float dx = ps[m][0] - ps[k][0], dy = ps[m][1] - ps[k][1], dz = ps[m][2] - ps[k][2];
        dist_s[m][k] = sqrtf(fmaxf(dx * dx + dy * dy + dz * dz, 1e-12f));
    }
#pragma unroll
    for (int i = 0; i < 4; ++i) {
        int c = i * 256 + t;
        int h = c >> 7, wi = c & 127;
        int point = wi >> 2, g4w = wi & 3;
        int col8 = h * 32 + g4w * 8;
        int cs = col8 ^ (((point >> 3) & 3) << 4);
        *(u16x8*)&V_s[point][cs] = *(const u16x8*)&qkv2[ballbase + 16384 + (size_t)c * 8];
    }
    __syncthreads();

    int lane = t & 63, wv = t >> 6;
    int r15 = lane & 15, g4 = lane >> 4;
    const float scale = 0.17677669529663687f;       // 1/sqrt(32)

#pragma unroll
    for (int hh = 0; hh < 2; ++hh) {
        int h = wv * 2 + hh;
        float sig = sigma[h];
        u16x8 aq[2], bk[2];
#pragma unroll
        for (int i = 0; i < 2; ++i) {
            aq[i] = *(const u16x8*)&qkv2[ballbase + h * 1024 + (size_t)(i * 16 + r15) * 32 + g4 * 8];
            bk[i] = *(const u16x8*)&qkv2[ballbase + 8192 + h * 1024 + (size_t)(i * 16 + r15) * 32 + g4 * 8];
        }
        f32x4 s[2][2];
#pragma unroll
        for (int i = 0; i < 2; ++i)
#pragma unroll
            for (int j = 0; j < 2; ++j) s[i][j] = (f32x4){0.f, 0.f, 0.f, 0.f};
#pragma unroll
        for (int i = 0; i < 2; ++i)
#pragma unroll
            for (int j = 0; j < 2; ++j)
                s[i][j] = mfma16(aq[i], bk[j], s[i][j]);

#pragma unroll
        for (int i = 0; i < 2; ++i) {
#pragma unroll
            for (int r = 0; r < 4; ++r) {
                int row = i * 16 + g4 * 4 + r;
                float v0 = s[i][0][r] * scale + sig * dist_s[row][r15];
                float v1 = s[i][1][r] * scale + sig * dist_s[row][16 + r15];
                float m = fmaxf(v0, v1);
                m = fmaxf(m, __shfl_xor(m, 1));
                m = fmaxf(m, __shfl_xor(m, 2));
                m = fmaxf(m, __shfl_xor(m, 4));
                m = fmaxf(m, __shfl_xor(m, 8));
                float e0 = __expf(v0 - m), e1 = __expf(v1 - m);
                float su = e0 + e1;
                su += __shfl_xor(su, 1);
                su += __shfl_xor(su, 2);
                su += __shfl_xor(su, 4);
                su += __shfl_xor(su, 8);
                float rin = 1.0f / su;
                P_s[wv][row][r15]      = f2bf(e0 * rin);
                P_s[wv][row][16 + r15] = f2bf(e1 * rin);
            }
        }
        u16x8 pa[2];
#pragma unroll
        for (int i = 0; i < 2; ++i)
            pa[i] = *(const u16x8*)&P_s[wv][i * 16 + r15][g4 * 8];
        u16x8 bv[2];
#pragma unroll
        for (int j = 0; j < 2; ++j) {
#pragma unroll
            for (int jj = 0; jj < 8; ++jj) {
                int kp = g4 * 8 + jj;
                int colv = h * 32 + j * 16 + r15;
                bv[j][jj] = V_s[kp][colv ^ (((kp >> 3) & 3) << 4)];
            }
        }
        f32x4 o[2][2];
#pragma unroll
        for (int i = 0; i < 2; ++i)
#pragma unroll
            for (int j = 0; j < 2; ++j) o[i][j] = (f32x4){0.f, 0.f, 0.f, 0.f};
#pragma unroll
        for (int i = 0; i < 2; ++i)
#pragma unroll
            for (int j = 0; j < 2; ++j)
                o[i][j] = mfma16(pa[i], bv[j], o[i][j]);
#pragma unroll
        for (int i = 0; i < 2; ++i)
#pragma unroll
            for (int j = 0; j < 2; ++j)
#pragma unroll
                for (int r = 0; r < 4; ++r) {
                    int row = i * 16 + g4 * 4 + r;
                    int col = h * 32 + j * 16 + r15;
                    ao_s[row][col] = f2bf(o[i][j][r]);
                }
    }
    __syncthreads();

    f32x4 pacc[4][2];
#pragma unroll
    for (int tt = 0; tt < 4; ++tt)
#pragma unroll
        for (int i = 0; i < 2; ++i) pacc[tt][i] = (f32x4){0.f, 0.f, 0.f, 0.f};
#pragma unroll
    for (int hk = 0; hk < 8; ++hk) {
        u16x8 apj[2];
#pragma unroll
        for (int i = 0; i < 2; ++i)
            apj[i] = *(const u16x8*)&ao_s[i * 16 + r15][hk * 32 + g4 * 8];
#pragma unroll
        for (int tt = 0; tt < 4; ++tt) {
            int gct = wv * 4 + tt;
            u16x8 b = *(const u16x8*)&wpF[(size_t)((gct * 8 + hk) * 64 + lane) * 8];
            pacc[tt][0] = mfma16(apj[0], b, pacc[tt][0]);
            pacc[tt][1] = mfma16(apj[1], b, pacc[tt][1]);
        }
    }
#pragma unroll
    for (int tt = 0; tt < 4; ++tt) {
        int ct = (wv * 4 + tt) * 16;
        float bb = bp[ct + r15];
#pragma unroll
        for (int i = 0; i < 2; ++i)
#pragma unroll
            for (int r = 0; r < 4; ++r) {
                int row = ball * MSZ + i * 16 + g4 * 4 + r;
                out[(size_t)row * 256 + ct + r15] = pacc[tt][i][r] + bb;
            }
    }
}

extern "C" void kernel_launch(void* const* d_in, const int* in_sizes, int n_in,
                              void* d_out, int out_size, void* d_ws, size_t ws_size,
                              hipStream_t stream) {
    (void)in_sizes; (void)n_in; (void)out_size; (void)ws_size;
    const float* x      = (const float*)d_in[0];
    const float* pos    = (const float*)d_in[1];
    const float* w_qkv  = (const float*)d_in[2];
    const float* b_qkv  = (const float*)d_in[3];
    const float* w_pe   = (const float*)d_in[4];
    const float* b_pe   = (const float*)d_in[5];
    const float* w_proj = (const float*)d_in[6];
    const float* b_proj = (const float*)d_in[7];
    const float* sigma  = (const float*)d_in[8];
    float* out = (float*)d_out;

    u16* qkv2   = (u16*)d_ws;                       // N*768 bf16 = 402.7 MB
    u16* wqkvT  = qkv2 + (size_t)NPTS * 768;        // 768*256 u16
    u16* wpF    = wqkvT + 768 * 256;                // 65536 u16
    float* bq   = (float*)(wpF + 65536);            // 768 f32

    k0_wprep<<<800, 256, 0, stream>>>(w_qkv, b_qkv, w_proj, wqkvT, wpF, bq);
    k1_qkv<<<4096, 256, 0, stream>>>(x, pos, w_pe, b_pe, wqkvT, bq, qkv2);
    k23_attnproj<<<NBALLS, 256, 0, stream>>>(pos, sigma, qkv2, wpF, b_proj, out);
}

// Round 13
// 585.187 us; speedup vs baseline: 1.3644x; 1.3644x over previous
//
#include <hip/hip_runtime.h>

#define NPTS   262144
#define NBALLS 8192
#define MSZ    32

typedef unsigned short u16;
typedef __attribute__((ext_vector_type(8))) unsigned short u16x8;
typedef __attribute__((ext_vector_type(4))) unsigned short u16x4;
typedef __attribute__((ext_vector_type(8))) __bf16 bf16x8;
typedef __attribute__((ext_vector_type(4))) float f32x4;
typedef __attribute__((ext_vector_type(2))) unsigned u32x2;

__device__ inline u16 f2bf(float f) {
    unsigned u = __builtin_bit_cast(unsigned, f);
    u += 0x7fffu + ((u >> 16) & 1u);           // RNE
    return (u16)(u >> 16);
}

__device__ inline unsigned pk2(float lo, float hi) {   // lo -> bits 0-15
    return (unsigned)f2bf(lo) | ((unsigned)f2bf(hi) << 16);
}

__device__ inline f32x4 mfma16(u16x8 a, u16x8 b, f32x4 c) {
    return __builtin_amdgcn_mfma_f32_16x16x32_bf16(
        __builtin_bit_cast(bf16x8, a), __builtin_bit_cast(bf16x8, b), c, 0, 0, 0);
}

__device__ inline void gload_lds16(const u16* g, u16* l) {
    __builtin_amdgcn_global_load_lds(
        (const __attribute__((address_space(1))) void*)g,
        (__attribute__((address_space(3))) void*)l, 16, 0, 0);
}

// ---------------- K0: weight prep (round-7/9 verified, unchanged) ------------
__global__ __launch_bounds__(256) void k0_wprep(const float* __restrict__ w_qkv,
                                                const float* __restrict__ b_qkv,
                                                const float* __restrict__ w_proj,
                                                u16* __restrict__ wqkvT,
                                                u16* __restrict__ wpF,
                                                float* __restrict__ bq) {
    int idx = blockIdx.x * 256 + threadIdx.x;
    if (idx < 768 * 256) {
        int cp = idx >> 8, r = idx & 255;
        int k = cp >> 8, rem = cp & 255, h = rem >> 5, e = rem & 31;
        int orig = h * 96 + e * 3 + k;
        wqkvT[cp * 256 + r] = f2bf(w_qkv[r * 768 + orig]);
        if (r == 0) bq[cp] = b_qkv[orig];
    } else {
        int tid2 = idx - 768 * 256;             // < 8192 (grid = 800 blocks)
        int lane = tid2 & 63, ch = tid2 >> 6;
        int hk = ch & 7, gct = ch >> 3;
        int r15 = lane & 15, g4 = lane >> 4;
        u16x8 o;
#pragma unroll
        for (int j = 0; j < 8; ++j)
            o[j] = f2bf(w_proj[(size_t)(hk * 32 + g4 * 8 + j) * 256 + gct * 16 + r15]);
        *(u16x8*)&wpF[(size_t)tid2 * 8] = o;
    }
}

// ---------------- K1: fused pos-embed + QKV GEMM (R9 + Astage aliased) ------
// Block = 128 rows (4 balls), 512 thr. A-staging reuses Bs[1] (dead until
// main-loop iter 0, whose gload is issued after the prologue's last barrier).
__global__ __launch_bounds__(512, 6) void k1_qkv(const float* __restrict__ x,
                                                 const float* __restrict__ pos,
                                                 const float* __restrict__ w_pe,
                                                 const float* __restrict__ b_pe,
                                                 const u16* __restrict__ wqkvT,
                                                 const float* __restrict__ bq,
                                                 u16* __restrict__ qkv2) {
    __shared__ __align__(16) u16 Bs[2][128 * 64];   // 32 KB dbuf (Bs[1] doubles as Astage)
    __shared__ float ps_s[384];
    __shared__ float ctr_s[4][3];
    __shared__ float rel_s[128][3];
    __shared__ float wpe_s[3][256];
    __shared__ float bpe_s[256];

    int id = blockIdx.x;
    int rt = (id >> 3) + (id & 7) * 256;            // bijective XCD swizzle (2048%8==0)
    int t = threadIdx.x;
    int lane = t & 63, wv = t >> 6;
    int r15 = lane & 15, g4 = lane >> 4;
    int wr = wv >> 1, wc = wv & 1;
    int rowbase = rt * 128;

    // ---- tables ----
    if (t < 384) ps_s[t] = pos[(size_t)rt * 384 + t];
    if (t < 256) bpe_s[t] = b_pe[t];
    for (int i = t; i < 768; i += 512) ((float*)wpe_s)[i] = w_pe[i];
    __syncthreads();
    if (t < 12) {
        int b = t / 3, m = t % 3;
        float s = 0.f;
#pragma unroll
        for (int j = 0; j < MSZ; ++j) s += ps_s[(b * 32 + j) * 3 + m];
        ctr_s[b][m] = s * (1.0f / MSZ);
    }
    __syncthreads();
    if (t < 384) {
        int p = t / 3, m = t % 3;
        ((float*)rel_s)[t] = ps_s[t] - ctr_s[p >> 5][m];
    }
    // issue B panel (ct=0,kt=0) early — drains at prologue __syncthreads
#pragma unroll
    for (int i = 0; i < 2; ++i) {
        int c = i * 512 + t;
        int row = c >> 3, sg = c & 7;
        gload_lds16(&wqkvT[(size_t)row * 256 + (sg ^ (row & 7)) * 8], &Bs[0][c * 8]);
    }
    __syncthreads();                                // rel_s ready

    // ---- embed -> register A-frags via Bs[1] as staging (R9 math verbatim) --
    u16* Ast = &Bs[1][0];
    u16x8 af[2][8];                                 // [row-frag][ks 0..7]
#pragma unroll
    for (int kt = 0; kt < 4; ++kt) {
#pragma unroll
        for (int i = 0; i < 2; ++i) {
            int c = i * 512 + t;
            int row = c >> 3, g = c & 7;
            int kk0 = kt * 64 + g * 8;
            float4 xa = *(const float4*)&x[(size_t)(rowbase + row) * 256 + kk0];
            float4 xb = *(const float4*)&x[(size_t)(rowbase + row) * 256 + kk0 + 4];
            float r0 = rel_s[row][0], r1 = rel_s[row][1], r2 = rel_s[row][2];
            u16x8 o;
#pragma unroll
            for (int m = 0; m < 8; ++m) {
                float xv = (m < 4) ? ((const float*)&xa)[m] : ((const float*)&xb)[m - 4];
                float v = fmaf(r0, wpe_s[0][kk0 + m],
                          fmaf(r1, wpe_s[1][kk0 + m],
                          fmaf(r2, wpe_s[2][kk0 + m], xv))) + bpe_s[kk0 + m];
                o[m] = f2bf(v);
            }
            *(u16x8*)&Ast[(row * 8 + (g ^ (row & 7))) * 8] = o;
        }
        __syncthreads();
#pragma unroll
        for (int ks = 0; ks < 2; ++ks)
#pragma unroll
            for (int i = 0; i < 2; ++i) {
                int R = wr * 32 + i * 16 + r15;
                af[i][2 * kt + ks] =
                    *(const u16x8*)&Ast[R * 64 + (((ks * 4 + g4) ^ (R & 7)) * 8)];
            }
        __syncthreads();
    }

    // ---- main loop: 6 ct × 4 kt, B dbuf, R9-verified barrier scheme --------
    f32x4 acc[4][2];
#pragma unroll
    for (int j = 0; j < 4; ++j)
#pragma unroll
        for (int i = 0; i < 2; ++i) acc[j][i] = (f32x4){0.f, 0.f, 0.f, 0.f};

    const int ball = rt * 4 + wr;
#pragma unroll
    for (int ct = 0; ct < 6; ++ct) {
#pragma unroll
        for (int kt = 0; kt < 4; ++kt) {
            int cur = kt & 1;
            if (kt < 3 || ct < 5) {
                int nct = (kt < 3) ? ct : ct + 1;
                int nkt = (kt < 3) ? kt + 1 : 0;
#pragma unroll
                for (int i = 0; i < 2; ++i) {
                    int c = i * 512 + t;
                    int row = c >> 3, sg = c & 7;
                    gload_lds16(&wqkvT[(size_t)(nct * 128 + row) * 256 + nkt * 64 + (sg ^ (row & 7)) * 8],
                                &Bs[cur ^ 1][c * 8]);
                }
            }
#pragma unroll
            for (int ks = 0; ks < 2; ++ks) {
                u16x8 b[4];
#pragma unroll
                for (int j = 0; j < 4; ++j) {
                    int C = wc * 64 + j * 16 + r15;
                    b[j] = *(const u16x8*)&Bs[cur][C * 64 + (((ks * 4 + g4) ^ (C & 7)) * 8)];
                }
                // swapped operands: C rows = cp (in-thread), cols = point (lane)
#pragma unroll
                for (int j = 0; j < 4; ++j)
#pragma unroll
                    for (int i = 0; i < 2; ++i)
                        acc[j][i] = mfma16(b[j], af[i][2 * kt + ks], acc[j][i]);
            }
            if (kt == 3) {
                // epilogue for this ct: packed 8B stores (round-8 verified)
#pragma unroll
                for (int j = 0; j < 4; ++j) {
                    int cp0 = ct * 128 + wc * 64 + j * 16 + g4 * 4;
                    float4 bias = *(const float4*)&bq[cp0];
                    int mat = cp0 >> 8, rem = cp0 & 255, h = rem >> 5, e0 = rem & 31;
                    size_t base = (size_t)ball * 24576 + mat * 8192 + h * 1024 + e0;
#pragma unroll
                    for (int i = 0; i < 2; ++i) {
                        int point = i * 16 + r15;
                        unsigned lo = pk2(acc[j][i][0] + bias.x, acc[j][i][1] + bias.y);
                        unsigned hi = pk2(acc[j][i][2] + bias.z, acc[j][i][3] + bias.w);
                        *(u32x2*)&qkv2[base + point * 32] = (u32x2){lo, hi};
                        acc[j][i] = (f32x4){0.f, 0.f, 0.f, 0.f};
                    }
                }
            }
            __syncthreads();
        }
    }
}

// ---------------- K23: fused attention + projection (round-7 verified) ------
__global__ __launch_bounds__(256) void k23_attnproj(const float* __restrict__ pos,
                                                    const float* __restrict__ sigma,
                                                    const u16* __restrict__ qkv2,
                                                    const u16* __restrict__ wpF,
                                                    const float* __restrict__ bp,
                                                    float* __restrict__ out) {
    int ball = blockIdx.x, t = threadIdx.x;
    __shared__ float ps[MSZ][3];
    __shared__ float dist_s[MSZ][33];
    __shared__ __align__(16) u16 V_s[MSZ][256];
    __shared__ __align__(16) u16 P_s[4][MSZ][40];
    __shared__ __align__(16) u16 ao_s[MSZ][264];

    const size_t ballbase = (size_t)ball * 24576;

    if (t < MSZ * 3) ((float*)ps)[t] = pos[(size_t)ball * (MSZ * 3) + t];
    __syncthreads();
    for (int p = t; p < 1024; p += 256) {
        int m = p >> 5, k = p & 31;
        float dx = ps[m][0] - ps[k][0], dy = ps[m][1] - ps[k][1], dz = ps[m][2] - ps[k][2];
        dist_s[m][k] = sqrtf(fmaxf(dx * dx + dy * dy + dz * dz, 1e-12f));
    }
#pragma unroll
    for (int i = 0; i < 4; ++i) {
        int c = i * 256 + t;
        int h = c >> 7, wi = c & 127;
        int point = wi >> 2, g4w = wi & 3;
        int col8 = h * 32 + g4w * 8;
        int cs = col8 ^ (((point >> 3) & 3) << 4);
        *(u16x8*)&V_s[point][cs] = *(const u16x8*)&qkv2[ballbase + 16384 + (size_t)c * 8];
    }
    __syncthreads();

    int lane = t & 63, wv = t >> 6;
    int r15 = lane & 15, g4 = lane >> 4;
    const float scale = 0.17677669529663687f;       // 1/sqrt(32)

#pragma unroll
    for (int hh = 0; hh < 2; ++hh) {
        int h = wv * 2 + hh;
        float sig = sigma[h];
        u16x8 aq[2], bk[2];
#pragma unroll
        for (int i = 0; i < 2; ++i) {
            aq[i] = *(const u16x8*)&qkv2[ballbase + h * 1024 + (size_t)(i * 16 + r15) * 32 + g4 * 8];
            bk[i] = *(const u16x8*)&qkv2[ballbase + 8192 + h * 1024 + (size_t)(i * 16 + r15) * 32 + g4 * 8];
        }
        f32x4 s[2][2];
#pragma unroll
        for (int i = 0; i < 2; ++i)
#pragma unroll
            for (int j = 0; j < 2; ++j) s[i][j] = (f32x4){0.f, 0.f, 0.f, 0.f};
#pragma unroll
        for (int i = 0; i < 2; ++i)
#pragma unroll
            for (int j = 0; j < 2; ++j)
                s[i][j] = mfma16(aq[i], bk[j], s[i][j]);

#pragma unroll
        for (int i = 0; i < 2; ++i) {
#pragma unroll
            for (int r = 0; r < 4; ++r) {
                int row = i * 16 + g4 * 4 + r;
                float v0 = s[i][0][r] * scale + sig * dist_s[row][r15];
                float v1 = s[i][1][r] * scale + sig * dist_s[row][16 + r15];
                float m = fmaxf(v0, v1);
                m = fmaxf(m, __shfl_xor(m, 1));
                m = fmaxf(m, __shfl_xor(m, 2));
                m = fmaxf(m, __shfl_xor(m, 4));
                m = fmaxf(m, __shfl_xor(m, 8));
                float e0 = __expf(v0 - m), e1 = __expf(v1 - m);
                float su = e0 + e1;
                su += __shfl_xor(su, 1);
                su += __shfl_xor(su, 2);
                su += __shfl_xor(su, 4);
                su += __shfl_xor(su, 8);
                float rin = 1.0f / su;
                P_s[wv][row][r15]      = f2bf(e0 * rin);
                P_s[wv][row][16 + r15] = f2bf(e1 * rin);
            }
        }
        u16x8 pa[2];
#pragma unroll
        for (int i = 0; i < 2; ++i)
            pa[i] = *(const u16x8*)&P_s[wv][i * 16 + r15][g4 * 8];
        u16x8 bv[2];
#pragma unroll
        for (int j = 0; j < 2; ++j) {
#pragma unroll
            for (int jj = 0; jj < 8; ++jj) {
                int kp = g4 * 8 + jj;
                int colv = h * 32 + j * 16 + r15;
                bv[j][jj] = V_s[kp][colv ^ (((kp >> 3) & 3) << 4)];
            }
        }
        f32x4 o[2][2];
#pragma unroll
        for (int i = 0; i < 2; ++i)
#pragma unroll
            for (int j = 0; j < 2; ++j) o[i][j] = (f32x4){0.f, 0.f, 0.f, 0.f};
#pragma unroll
        for (int i = 0; i < 2; ++i)
#pragma unroll
            for (int j = 0; j < 2; ++j)
                o[i][j] = mfma16(pa[i], bv[j], o[i][j]);
#pragma unroll
        for (int i = 0; i < 2; ++i)
#pragma unroll
            for (int j = 0; j < 2; ++j)
#pragma unroll
                for (int r = 0; r < 4; ++r) {
                    int row = i * 16 + g4 * 4 + r;
                    int col = h * 32 + j * 16 + r15;
                    ao_s[row][col] = f2bf(o[i][j][r]);
                }
    }
    __syncthreads();

    f32x4 pacc[4][2];
#pragma unroll
    for (int tt = 0; tt < 4; ++tt)
#pragma unroll
        for (int i = 0; i < 2; ++i) pacc[tt][i] = (f32x4){0.f, 0.f, 0.f, 0.f};
#pragma unroll
    for (int hk = 0; hk < 8; ++hk) {
        u16x8 apj[2];
#pragma unroll
        for (int i = 0; i < 2; ++i)
            apj[i] = *(const u16x8*)&ao_s[i * 16 + r15][hk * 32 + g4 * 8];
#pragma unroll
        for (int tt = 0; tt < 4; ++tt) {
            int gct = wv * 4 + tt;
            u16x8 b = *(const u16x8*)&wpF[(size_t)((gct * 8 + hk) * 64 + lane) * 8];
            pacc[tt][0] = mfma16(apj[0], b, pacc[tt][0]);
            pacc[tt][1] = mfma16(apj[1], b, pacc[tt][1]);
        }
    }
#pragma unroll
    for (int tt = 0; tt < 4; ++tt) {
        int ct = (wv * 4 + tt) * 16;
        float bb = bp[ct + r15];
#pragma unroll
        for (int i = 0; i < 2; ++i)
#pragma unroll
            for (int r = 0; r < 4; ++r) {
                int row = ball * MSZ + i * 16 + g4 * 4 + r;
                out[(size_t)row * 256 + ct + r15] = pacc[tt][i][r] + bb;
            }
    }
}

extern "C" void kernel_launch(void* const* d_in, const int* in_sizes, int n_in,
                              void* d_out, int out_size, void* d_ws, size_t ws_size,
                              hipStream_t stream) {
    (void)in_sizes; (void)n_in; (void)out_size; (void)ws_size;
    const float* x      = (const float*)d_in[0];
    const float* pos    = (const float*)d_in[1];
    const float* w_qkv  = (const float*)d_in[2];
    const float* b_qkv  = (const float*)d_in[3];
    const float* w_pe   = (const float*)d_in[4];
    const float* b_pe   = (const float*)d_in[5];
    const float* w_proj = (const float*)d_in[6];
    const float* b_proj = (const float*)d_in[7];
    const float* sigma  = (const float*)d_in[8];
    float* out = (float*)d_out;

    u16* qkv2   = (u16*)d_ws;                       // N*768 bf16 = 402.7 MB
    u16* wqkvT  = qkv2 + (size_t)NPTS * 768;        // 768*256 u16
    u16* wpF    = wqkvT + 768 * 256;                // 65536 u16
    float* bq   = (float*)(wpF + 65536);            // 768 f32

    k0_wprep<<<800, 256, 0, stream>>>(w_qkv, b_qkv, w_proj, wqkvT, wpF, bq);
    k1_qkv<<<2048, 512, 0, stream>>>(x, pos, w_pe, b_pe, wqkvT, bq, qkv2);
    k23_attnproj<<<NBALLS, 256, 0, stream>>>(pos, sigma, qkv2, wpF, b_proj, out);
}

// Round 14
// 421.127 us; speedup vs baseline: 1.8959x; 1.3896x over previous
//
#include <hip/hip_runtime.h>

#define NPTS   262144
#define NBALLS 8192
#define MSZ    32

typedef unsigned short u16;
typedef __attribute__((ext_vector_type(8))) unsigned short u16x8;
typedef __attribute__((ext_vector_type(4))) unsigned short u16x4;
typedef __attribute__((ext_vector_type(8))) __bf16 bf16x8;
typedef __attribute__((ext_vector_type(4))) float f32x4;
typedef __attribute__((ext_vector_type(2))) unsigned u32x2;

__device__ inline u16 f2bf(float f) {
    unsigned u = __builtin_bit_cast(unsigned, f);
    u += 0x7fffu + ((u >> 16) & 1u);           // RNE
    return (u16)(u >> 16);
}

__device__ inline unsigned pk2(float lo, float hi) {   // lo -> bits 0-15
    return (unsigned)f2bf(lo) | ((unsigned)f2bf(hi) << 16);
}

__device__ inline f32x4 mfma16(u16x8 a, u16x8 b, f32x4 c) {
    return __builtin_amdgcn_mfma_f32_16x16x32_bf16(
        __builtin_bit_cast(bf16x8, a), __builtin_bit_cast(bf16x8, b), c, 0, 0, 0);
}

__device__ inline void gload_lds16(const u16* g, u16* l) {
    __builtin_amdgcn_global_load_lds(
        (const __attribute__((address_space(1))) void*)g,
        (__attribute__((address_space(3))) void*)l, 16, 0, 0);
}

// ---------------- K0: weight prep (round-7/9 verified, unchanged) ------------
__global__ __launch_bounds__(256) void k0_wprep(const float* __restrict__ w_qkv,
                                                const float* __restrict__ b_qkv,
                                                const float* __restrict__ w_proj,
                                                u16* __restrict__ wqkvT,
                                                u16* __restrict__ wpF,
                                                float* __restrict__ bq) {
    int idx = blockIdx.x * 256 + threadIdx.x;
    if (idx < 768 * 256) {
        int cp = idx >> 8, r = idx & 255;
        int k = cp >> 8, rem = cp & 255, h = rem >> 5, e = rem & 31;
        int orig = h * 96 + e * 3 + k;
        wqkvT[cp * 256 + r] = f2bf(w_qkv[r * 768 + orig]);
        if (r == 0) bq[cp] = b_qkv[orig];
    } else {
        int tid2 = idx - 768 * 256;             // < 8192 (grid = 800 blocks)
        int lane = tid2 & 63, ch = tid2 >> 6;
        int hk = ch & 7, gct = ch >> 3;
        int r15 = lane & 15, g4 = lane >> 4;
        u16x8 o;
#pragma unroll
        for (int j = 0; j < 8; ++j)
            o[j] = f2bf(w_proj[(size_t)(hk * 32 + g4 * 8 + j) * 256 + gct * 16 + r15]);
        *(u16x8*)&wpF[(size_t)tid2 * 8] = o;
    }
}

// ---------------- K1: fused pos-embed + QKV GEMM (R13 alias, R9 reg budget) --
// Block = 128 rows (4 balls), 512 thr. A-staging reuses Bs[1] (dead until
// main-loop iter 0). launch_bounds(512,4): VGPR cap 128 -> no spill (R9: 64).
// LDS 40 KB -> up to 4 blocks/CU.
__global__ __launch_bounds__(512, 4) void k1_qkv(const float* __restrict__ x,
                                                 const float* __restrict__ pos,
                                                 const float* __restrict__ w_pe,
                                                 const float* __restrict__ b_pe,
                                                 const u16* __restrict__ wqkvT,
                                                 const float* __restrict__ bq,
                                                 u16* __restrict__ qkv2) {
    __shared__ __align__(16) u16 Bs[2][128 * 64];   // 32 KB dbuf (Bs[1] doubles as Astage)
    __shared__ float ps_s[384];
    __shared__ float ctr_s[4][3];
    __shared__ float rel_s[128][3];
    __shared__ float wpe_s[3][256];
    __shared__ float bpe_s[256];

    int id = blockIdx.x;
    int rt = (id >> 3) + (id & 7) * 256;            // bijective XCD swizzle (2048%8==0)
    int t = threadIdx.x;
    int lane = t & 63, wv = t >> 6;
    int r15 = lane & 15, g4 = lane >> 4;
    int wr = wv >> 1, wc = wv & 1;
    int rowbase = rt * 128;

    // ---- tables ----
    if (t < 384) ps_s[t] = pos[(size_t)rt * 384 + t];
    if (t < 256) bpe_s[t] = b_pe[t];
    for (int i = t; i < 768; i += 512) ((float*)wpe_s)[i] = w_pe[i];
    __syncthreads();
    if (t < 12) {
        int b = t / 3, m = t % 3;
        float s = 0.f;
#pragma unroll
        for (int j = 0; j < MSZ; ++j) s += ps_s[(b * 32 + j) * 3 + m];
        ctr_s[b][m] = s * (1.0f / MSZ);
    }
    __syncthreads();
    if (t < 384) {
        int p = t / 3, m = t % 3;
        ((float*)rel_s)[t] = ps_s[t] - ctr_s[p >> 5][m];
    }
    // issue B panel (ct=0,kt=0) early — drains at prologue __syncthreads
#pragma unroll
    for (int i = 0; i < 2; ++i) {
        int c = i * 512 + t;
        int row = c >> 3, sg = c & 7;
        gload_lds16(&wqkvT[(size_t)row * 256 + (sg ^ (row & 7)) * 8], &Bs[0][c * 8]);
    }
    __syncthreads();                                // rel_s ready

    // ---- embed -> register A-frags via Bs[1] as staging (R9 math verbatim) --
    u16* Ast = &Bs[1][0];
    u16x8 af[2][8];                                 // [row-frag][ks 0..7]
#pragma unroll
    for (int kt = 0; kt < 4; ++kt) {
#pragma unroll
        for (int i = 0; i < 2; ++i) {
            int c = i * 512 + t;
            int row = c >> 3, g = c & 7;
            int kk0 = kt * 64 + g * 8;
            float4 xa = *(const float4*)&x[(size_t)(rowbase + row) * 256 + kk0];
            float4 xb = *(const float4*)&x[(size_t)(rowbase + row) * 256 + kk0 + 4];
            float r0 = rel_s[row][0], r1 = rel_s[row][1], r2 = rel_s[row][2];
            u16x8 o;
#pragma unroll
            for (int m = 0; m < 8; ++m) {
                float xv = (m < 4) ? ((const float*)&xa)[m] : ((const float*)&xb)[m - 4];
                float v = fmaf(r0, wpe_s[0][kk0 + m],
                          fmaf(r1, wpe_s[1][kk0 + m],
                          fmaf(r2, wpe_s[2][kk0 + m], xv))) + bpe_s[kk0 + m];
                o[m] = f2bf(v);
            }
            *(u16x8*)&Ast[(row * 8 + (g ^ (row & 7))) * 8] = o;
        }
        __syncthreads();
#pragma unroll
        for (int ks = 0; ks < 2; ++ks)
#pragma unroll
            for (int i = 0; i < 2; ++i) {
                int R = wr * 32 + i * 16 + r15;
                af[i][2 * kt + ks] =
                    *(const u16x8*)&Ast[R * 64 + (((ks * 4 + g4) ^ (R & 7)) * 8)];
            }
        __syncthreads();
    }

    // ---- main loop: 6 ct × 4 kt, B dbuf, R9-verified barrier scheme --------
    f32x4 acc[4][2];
#pragma unroll
    for (int j = 0; j < 4; ++j)
#pragma unroll
        for (int i = 0; i < 2; ++i) acc[j][i] = (f32x4){0.f, 0.f, 0.f, 0.f};

    const int ball = rt * 4 + wr;
#pragma unroll
    for (int ct = 0; ct < 6; ++ct) {
#pragma unroll
        for (int kt = 0; kt < 4; ++kt) {
            int cur = kt & 1;
            if (kt < 3 || ct < 5) {
                int nct = (kt < 3) ? ct : ct + 1;
                int nkt = (kt < 3) ? kt + 1 : 0;
#pragma unroll
                for (int i = 0; i < 2; ++i) {
                    int c = i * 512 + t;
                    int row = c >> 3, sg = c & 7;
                    gload_lds16(&wqkvT[(size_t)(nct * 128 + row) * 256 + nkt * 64 + (sg ^ (row & 7)) * 8],
                                &Bs[cur ^ 1][c * 8]);
                }
            }
#pragma unroll
            for (int ks = 0; ks < 2; ++ks) {
                u16x8 b[4];
#pragma unroll
                for (int j = 0; j < 4; ++j) {
                    int C = wc * 64 + j * 16 + r15;
                    b[j] = *(const u16x8*)&Bs[cur][C * 64 + (((ks * 4 + g4) ^ (C & 7)) * 8)];
                }
                // swapped operands: C rows = cp (in-thread), cols = point (lane)
#pragma unroll
                for (int j = 0; j < 4; ++j)
#pragma unroll
                    for (int i = 0; i < 2; ++i)
                        acc[j][i] = mfma16(b[j], af[i][2 * kt + ks], acc[j][i]);
            }
            if (kt == 3) {
                // epilogue for this ct: packed 8B stores (round-8 verified)
#pragma unroll
                for (int j = 0; j < 4; ++j) {
                    int cp0 = ct * 128 + wc * 64 + j * 16 + g4 * 4;
                    float4 bias = *(const float4*)&bq[cp0];
                    int mat = cp0 >> 8, rem = cp0 & 255, h = rem >> 5, e0 = rem & 31;
                    size_t base = (size_t)ball * 24576 + mat * 8192 + h * 1024 + e0;
#pragma unroll
                    for (int i = 0; i < 2; ++i) {
                        int point = i * 16 + r15;
                        unsigned lo = pk2(acc[j][i][0] + bias.x, acc[j][i][1] + bias.y);
                        unsigned hi = pk2(acc[j][i][2] + bias.z, acc[j][i][3] + bias.w);
                        *(u32x2*)&qkv2[base + point * 32] = (u32x2){lo, hi};
                        acc[j][i] = (f32x4){0.f, 0.f, 0.f, 0.f};
                    }
                }
            }
            __syncthreads();
        }
    }
}

// ---------------- K23: fused attention + projection (round-7 verified) ------
__global__ __launch_bounds__(256) void k23_attnproj(const float* __restrict__ pos,
                                                    const float* __restrict__ sigma,
                                                    const u16* __restrict__ qkv2,
                                                    const u16* __restrict__ wpF,
                                                    const float* __restrict__ bp,
                                                    float* __restrict__ out) {
    int ball = blockIdx.x, t = threadIdx.x;
    __shared__ float ps[MSZ][3];
    __shared__ float dist_s[MSZ][33];
    __shared__ __align__(16) u16 V_s[MSZ][256];
    __shared__ __align__(16) u16 P_s[4][MSZ][40];
    __shared__ __align__(16) u16 ao_s[MSZ][264];

    const size_t ballbase = (size_t)ball * 24576;

    if (t < MSZ * 3) ((float*)ps)[t] = pos[(size_t)ball * (MSZ * 3) + t];
    __syncthreads();
    for (int p = t; p < 1024; p += 256) {
        int m = p >> 5, k = p & 31;
        float dx = ps[m][0] - ps[k][0], dy = ps[m][1] - ps[k][1], dz = ps[m][2] - ps[k][2];
        dist_s[m][k] = sqrtf(fmaxf(dx * dx + dy * dy + dz * dz, 1e-12f));
    }
#pragma unroll
    for (int i = 0; i < 4; ++i) {
        int c = i * 256 + t;
        int h = c >> 7, wi = c & 127;
        int point = wi >> 2, g4w = wi & 3;
        int col8 = h * 32 + g4w * 8;
        int cs = col8 ^ (((point >> 3) & 3) << 4);
        *(u16x8*)&V_s[point][cs] = *(const u16x8*)&qkv2[ballbase + 16384 + (size_t)c * 8];
    }
    __syncthreads();

    int lane = t & 63, wv = t >> 6;
    int r15 = lane & 15, g4 = lane >> 4;
    const float scale = 0.17677669529663687f;       // 1/sqrt(32)

#pragma unroll
    for (int hh = 0; hh < 2; ++hh) {
        int h = wv * 2 + hh;
        float sig = sigma[h];
        u16x8 aq[2], bk[2];
#pragma unroll
        for (int i = 0; i < 2; ++i) {
            aq[i] = *(const u16x8*)&qkv2[ballbase + h * 1024 + (size_t)(i * 16 + r15) * 32 + g4 * 8];
            bk[i] = *(const u16x8*)&qkv2[ballbase + 8192 + h * 1024 + (size_t)(i * 16 + r15) * 32 + g4 * 8];
        }
        f32x4 s[2][2];
#pragma unroll
        for (int i = 0; i < 2; ++i)
#pragma unroll
            for (int j = 0; j < 2; ++j) s[i][j] = (f32x4){0.f, 0.f, 0.f, 0.f};
#pragma unroll
        for (int i = 0; i < 2; ++i)
#pragma unroll
            for (int j = 0; j < 2; ++j)
                s[i][j] = mfma16(aq[i], bk[j], s[i][j]);

#pragma unroll
        for (int i = 0; i < 2; ++i) {
#pragma unroll
            for (int r = 0; r < 4; ++r) {
                int row = i * 16 + g4 * 4 + r;
                float v0 = s[i][0][r] * scale + sig * dist_s[row][r15];
                float v1 = s[i][1][r] * scale + sig * dist_s[row][16 + r15];
                float m = fmaxf(v0, v1);
                m = fmaxf(m, __shfl_xor(m, 1));
                m = fmaxf(m, __shfl_xor(m, 2));
                m = fmaxf(m, __shfl_xor(m, 4));
                m = fmaxf(m, __shfl_xor(m, 8));
                float e0 = __expf(v0 - m), e1 = __expf(v1 - m);
                float su = e0 + e1;
                su += __shfl_xor(su, 1);
                su += __shfl_xor(su, 2);
                su += __shfl_xor(su, 4);
                su += __shfl_xor(su, 8);
                float rin = 1.0f / su;
                P_s[wv][row][r15]      = f2bf(e0 * rin);
                P_s[wv][row][16 + r15] = f2bf(e1 * rin);
            }
        }
        u16x8 pa[2];
#pragma unroll
        for (int i = 0; i < 2; ++i)
            pa[i] = *(const u16x8*)&P_s[wv][i * 16 + r15][g4 * 8];
        u16x8 bv[2];
#pragma unroll
        for (int j = 0; j < 2; ++j) {
#pragma unroll
            for (int jj = 0; jj < 8; ++jj) {
                int kp = g4 * 8 + jj;
                int colv = h * 32 + j * 16 + r15;
                bv[j][jj] = V_s[kp][colv ^ (((kp >> 3) & 3) << 4)];
            }
        }
        f32x4 o[2][2];
#pragma unroll
        for (int i = 0; i < 2; ++i)
#pragma unroll
            for (int j = 0; j < 2; ++j) o[i][j] = (f32x4){0.f, 0.f, 0.f, 0.f};
#pragma unroll
        for (int i = 0; i < 2; ++i)
#pragma unroll
            for (int j = 0; j < 2; ++j)
                o[i][j] = mfma16(pa[i], bv[j], o[i][j]);
#pragma unroll
        for (int i = 0; i < 2; ++i)
#pragma unroll
            for (int j = 0; j < 2; ++j)
#pragma unroll
                for (int r = 0; r < 4; ++r) {
                    int row = i * 16 + g4 * 4 + r;
                    int col = h * 32 + j * 16 + r15;
                    ao_s[row][col] = f2bf(o[i][j][r]);
                }
    }
    __syncthreads();

    f32x4 pacc[4][2];
#pragma unroll
    for (int tt = 0; tt < 4; ++tt)
#pragma unroll
        for (int i = 0; i < 2; ++i) pacc[tt][i] = (f32x4){0.f, 0.f, 0.f, 0.f};
#pragma unroll
    for (int hk = 0; hk < 8; ++hk) {
        u16x8 apj[2];
#pragma unroll
        for (int i = 0; i < 2; ++i)
            apj[i] = *(const u16x8*)&ao_s[i * 16 + r15][hk * 32 + g4 * 8];
#pragma unroll
        for (int tt = 0; tt < 4; ++tt) {
            int gct = wv * 4 + tt;
            u16x8 b = *(const u16x8*)&wpF[(size_t)((gct * 8 + hk) * 64 + lane) * 8];
            pacc[tt][0] = mfma16(apj[0], b, pacc[tt][0]);
            pacc[tt][1] = mfma16(apj[1], b, pacc[tt][1]);
        }
    }
#pragma unroll
    for (int tt = 0; tt < 4; ++tt) {
        int ct = (wv * 4 + tt) * 16;
        float bb = bp[ct + r15];
#pragma unroll
        for (int i = 0; i < 2; ++i)
#pragma unroll
            for (int r = 0; r < 4; ++r) {
                int row = ball * MSZ + i * 16 + g4 * 4 + r;
                out[(size_t)row * 256 + ct + r15] = pacc[tt][i][r] + bb;
            }
    }
}

extern "C" void kernel_launch(void* const* d_in, const int* in_sizes, int n_in,
                              void* d_out, int out_size, void* d_ws, size_t ws_size,
                              hipStream_t stream) {
    (void)in_sizes; (void)n_in; (void)out_size; (void)ws_size;
    const float* x      = (const float*)d_in[0];
    const float* pos    = (const float*)d_in[1];
    const float* w_qkv  = (const float*)d_in[2];
    const float* b_qkv  = (const float*)d_in[3];
    const float* w_pe   = (const float*)d_in[4];
    const float* b_pe   = (const float*)d_in[5];
    const float* w_proj = (const float*)d_in[6];
    const float* b_proj = (const float*)d_in[7];
    const float* sigma  = (const float*)d_in[8];
    float* out = (float*)d_out;

    u16* qkv2   = (u16*)d_ws;                       // N*768 bf16 = 402.7 MB
    u16* wqkvT  = qkv2 + (size_t)NPTS * 768;        // 768*256 u16
    u16* wpF    = wqkvT + 768 * 256;                // 65536 u16
    float* bq   = (float*)(wpF + 65536);            // 768 f32

    k0_wprep<<<800, 256, 0, stream>>>(w_qkv, b_qkv, w_proj, wqkvT, wpF, bq);
    k1_qkv<<<2048, 512, 0, stream>>>(x, pos, w_pe, b_pe, wqkvT, bq, qkv2);
    k23_attnproj<<<NBALLS, 256, 0, stream>>>(pos, sigma, qkv2, wpF, b_proj, out);
}